// Round 1
// baseline (594.375 us; speedup 1.0000x reference)
//
#include <hip/hip_runtime.h>
#include <hip/hip_bf16.h>

#define N_SPK 1024
#define M_UTT 20
#define D_DIM 768
#define NM_ROWS (N_SPK * M_UTT)   // 20480 utterances / rows

static constexpr float EPS = 1e-8f;

typedef __attribute__((ext_vector_type(8))) short short8;   // 8 x bf16 (4 VGPRs)
typedef __attribute__((ext_vector_type(4))) float floatx4;  // MFMA accumulator

// ---------------------------------------------------------------------------
// Kernel 1: centroids = mean over M of raw embeddings, then L2-normalize,
// store as bf16. One block (256 thr) per speaker; 768 = 3*256 elems/thread.
// ---------------------------------------------------------------------------
__global__ void centroid_kernel(const float* __restrict__ emb,
                                __hip_bfloat16* __restrict__ chat) {
    const int i = blockIdx.x;     // speaker
    const int t = threadIdx.x;    // 0..255
    const float* base = emb + (size_t)i * M_UTT * D_DIM;

    float c[3];
    float ss = 0.f;
    #pragma unroll
    for (int r = 0; r < 3; ++r) {
        const int d = t + r * 256;
        float s = 0.f;
        #pragma unroll
        for (int m = 0; m < M_UTT; ++m) s += base[m * D_DIM + d];
        c[r] = s * (1.0f / M_UTT);
        ss += c[r] * c[r];
    }
    __shared__ float red[256];
    red[t] = ss;
    __syncthreads();
    for (int ofs = 128; ofs > 0; ofs >>= 1) {
        if (t < ofs) red[t] += red[t + ofs];
        __syncthreads();
    }
    const float rn = 1.0f / fmaxf(sqrtf(red[0]), EPS);
    #pragma unroll
    for (int r = 0; r < 3; ++r) {
        const int d = t + r * 256;
        chat[(size_t)i * D_DIM + d] = __float2bfloat16(c[r] * rn);
    }
}

// ---------------------------------------------------------------------------
// Kernel 2: per-utterance L2 normalize; write bf16 Ehat laid out [m][i][d]
// so GEMM row u = m*N + i (16-row tiles never cross an m boundary).
// One block per utterance.
// ---------------------------------------------------------------------------
__global__ void ehat_kernel(const float* __restrict__ emb,
                            __hip_bfloat16* __restrict__ ehat) {
    const int u = blockIdx.x;          // 0..20479, input order (i, m)
    const int i = u / M_UTT;
    const int m = u % M_UTT;
    const int t = threadIdx.x;
    const float* src = emb + ((size_t)i * M_UTT + m) * D_DIM;

    float v[3];
    float ss = 0.f;
    #pragma unroll
    for (int r = 0; r < 3; ++r) {
        v[r] = src[t + r * 256];
        ss += v[r] * v[r];
    }
    __shared__ float red[256];
    red[t] = ss;
    __syncthreads();
    for (int ofs = 128; ofs > 0; ofs >>= 1) {
        if (t < ofs) red[t] += red[t + ofs];
        __syncthreads();
    }
    const float rn = 1.0f / fmaxf(sqrtf(red[0]), EPS);
    __hip_bfloat16* dst = ehat + ((size_t)m * N_SPK + i) * D_DIM;
    #pragma unroll
    for (int r = 0; r < 3; ++r) dst[t + r * 256] = __float2bfloat16(v[r] * rn);
}

// ---------------------------------------------------------------------------
// Kernel 3: S[u][j] = Ehat[u] . Chat[j]  (both row-major [row][d], i.e. the
// B^T GEMM). One wave per 16x16 output tile, K-loop of 24 MFMA 16x16x32.
// A-frag / B-frag layout: row = lane&15, k = (lane>>4)*8 + j  (verified m89).
// D layout: col = lane&15, row = (lane>>4)*4 + reg              (m89/m91).
// ---------------------------------------------------------------------------
__global__ void gemm_kernel(const __hip_bfloat16* __restrict__ ehat,
                            const __hip_bfloat16* __restrict__ chat,
                            float* __restrict__ S) {
    const int wave = (blockIdx.x << 2) + (threadIdx.x >> 6);
    const int lane = threadIdx.x & 63;
    const int tj = wave & 63;          // 64 j-tiles  (1024/16)
    const int tu = wave >> 6;          // 1280 u-tiles (20480/16)
    const int opr = lane & 15;         // operand row
    const int quad = lane >> 4;        // 0..3

    const short* A = (const short*)ehat + ((size_t)(tu * 16 + opr)) * D_DIM + quad * 8;
    const short* B = (const short*)chat + ((size_t)(tj * 16 + opr)) * D_DIM + quad * 8;

    floatx4 acc = {0.f, 0.f, 0.f, 0.f};
    #pragma unroll
    for (int k = 0; k < D_DIM; k += 32) {
        short8 a = *(const short8*)(A + k);
        short8 b = *(const short8*)(B + k);
        acc = __builtin_amdgcn_mfma_f32_16x16x32_bf16(a, b, acc, 0, 0, 0);
    }
    const int j = tj * 16 + opr;              // output col = lane&15
    const int ubase = tu * 16 + quad * 4;     // output row = quad*4 + r
    #pragma unroll
    for (int r = 0; r < 4; ++r) {
        S[(size_t)(ubase + r) * N_SPK + j] = acc[r];
    }
}

// ---------------------------------------------------------------------------
// Kernel 4: partial online-LSE over i (the GEMM row dim) for each (m, j).
// Block = (m, j-tile of 256, i-chunk of 256); thread owns one j, loops 256 i.
// Reads are coalesced across j. Writes (pmax, psum) per [ic][m][j].
// ---------------------------------------------------------------------------
__global__ void lse_partial_kernel(const float* __restrict__ S,
                                   const float* __restrict__ wp,
                                   const float* __restrict__ bp,
                                   float* __restrict__ pmax,
                                   float* __restrict__ psum) {
    const int blk = blockIdx.x;        // 20 * 4 * 4 = 320
    const int ic = blk & 3;
    const int jt = (blk >> 2) & 3;
    const int m  = blk >> 4;
    const int j = jt * 256 + threadIdx.x;
    const float w = wp[0], b = bp[0];

    const float* Sm = S + ((size_t)m * N_SPK + ic * 256) * N_SPK + j;
    float mx = -1e30f, sm = 0.f;
    #pragma unroll 4
    for (int ii = 0; ii < 256; ++ii) {
        const float l = w * Sm[(size_t)ii * N_SPK] + b;
        const float nm = fmaxf(mx, l);
        sm = sm * __expf(mx - nm) + __expf(l - nm);
        mx = nm;
    }
    const int p = (ic * M_UTT + m) * N_SPK + j;
    pmax[p] = mx;
    psum[p] = sm;
}

// ---------------------------------------------------------------------------
// Kernel 5: combine partials -> LSE per (m,j); gather target logit at
// i* = (m*N + j) / M (the reference's label indexing); mean-reduce.
// Single block, no atomics (so no d_out pre-zeroing needed).
// ---------------------------------------------------------------------------
__global__ void finalize_kernel(const float* __restrict__ S,
                                const float* __restrict__ pmax,
                                const float* __restrict__ psum,
                                const float* __restrict__ wp,
                                const float* __restrict__ bp,
                                float* __restrict__ out) {
    const int t = threadIdx.x;
    const float w = wp[0], b = bp[0];
    float acc = 0.f;
    for (int p = t; p < M_UTT * N_SPK; p += 256) {
        const int m = p >> 10;         // N_SPK = 1024
        const int j = p & 1023;
        float M0 = -1e30f, Ss = 0.f;
        #pragma unroll
        for (int ic = 0; ic < 4; ++ic) {
            const int q = (ic * M_UTT + m) * N_SPK + j;
            const float pm = pmax[q], ps = psum[q];
            const float nm = fmaxf(M0, pm);
            Ss = Ss * __expf(M0 - nm) + ps * __expf(pm - nm);
            M0 = nm;
        }
        const float lse = M0 + __logf(Ss);
        const int istar = (m * N_SPK + j) / M_UTT;   // label column
        const float st = S[((size_t)m * N_SPK + istar) * N_SPK + j];
        acc += (w * st + b) - lse;
    }
    __shared__ float red[256];
    red[t] = acc;
    __syncthreads();
    for (int ofs = 128; ofs > 0; ofs >>= 1) {
        if (t < ofs) red[t] += red[t + ofs];
        __syncthreads();
    }
    if (t == 0) out[0] = -red[0] / (float)(M_UTT * N_SPK);
}

// ---------------------------------------------------------------------------
extern "C" void kernel_launch(void* const* d_in, const int* in_sizes, int n_in,
                              void* d_out, int out_size, void* d_ws, size_t ws_size,
                              hipStream_t stream) {
    const float* emb = (const float*)d_in[0];
    const float* wp  = (const float*)d_in[1];
    const float* bp  = (const float*)d_in[2];
    float* out = (float*)d_out;

    char* ws = (char*)d_ws;
    // layout (bytes):
    //   Ehat bf16 [M][N][D]      : 20*1024*768*2 = 31,457,280
    //   Chat bf16 [N][D]         : 1024*768*2    =  1,572,864   @ 31,457,280
    //   S    f32  [M][N_i][N_j]  : 20*1024*1024*4= 83,886,080   @ 33,030,144
    //   pmax f32  [4][M][N_j]    : 4*20*1024*4   =    327,680   @ 116,916,224
    //   psum f32  [4][M][N_j]    :                   327,680    @ 117,243,904
    __hip_bfloat16* ehat = (__hip_bfloat16*)(ws);
    __hip_bfloat16* chat = (__hip_bfloat16*)(ws + 31457280);
    float* S    = (float*)(ws + 33030144);
    float* pmax = (float*)(ws + 116916224);
    float* psum = (float*)(ws + 117243904);

    centroid_kernel<<<dim3(N_SPK), dim3(256), 0, stream>>>(emb, chat);
    ehat_kernel<<<dim3(NM_ROWS), dim3(256), 0, stream>>>(emb, ehat);
    gemm_kernel<<<dim3((NM_ROWS / 16) * (N_SPK / 16) / 4), dim3(256), 0, stream>>>(ehat, chat, S);
    lse_partial_kernel<<<dim3(M_UTT * 4 * 4), dim3(256), 0, stream>>>(S, wp, bp, pmax, psum);
    finalize_kernel<<<dim3(1), dim3(256), 0, stream>>>(S, pmax, psum, wp, bp, out);
}

// Round 2
// 209.755 us; speedup vs baseline: 2.8337x; 2.8337x over previous
//
#include <hip/hip_runtime.h>
#include <hip/hip_bf16.h>
#include <cstdint>

#define N_SPK 1024
#define M_UTT 20
#define D_DIM 768
#define NM_ROWS (N_SPK * M_UTT)   // 20480 utterances / rows

static constexpr float EPS = 1e-8f;

typedef __attribute__((ext_vector_type(8))) short short8;   // 8 x bf16 (4 VGPRs)
typedef __attribute__((ext_vector_type(4))) float floatx4;  // MFMA accumulator

// async 16B global -> LDS (wave-uniform base + lane*16 ordering holds for our
// addressing: lds offset == threadIdx.x*16 within each issue)
__device__ __forceinline__ void load16_to_lds(const void* g, void* l) {
    __builtin_amdgcn_global_load_lds(
        (const __attribute__((address_space(1))) uint32_t*)g,
        (__attribute__((address_space(3))) uint32_t*)l, 16, 0, 0);
}

// ---------------------------------------------------------------------------
// Kernel 1: centroids = mean over M, L2-normalize, store bf16.
// One block (256 thr) per speaker; 768 = 3*256.
// ---------------------------------------------------------------------------
__global__ void centroid_kernel(const float* __restrict__ emb,
                                __hip_bfloat16* __restrict__ chat) {
    const int i = blockIdx.x;
    const int t = threadIdx.x;
    const float* base = emb + (size_t)i * M_UTT * D_DIM;

    float c[3];
    float ss = 0.f;
    #pragma unroll
    for (int r = 0; r < 3; ++r) {
        const int d = t + r * 256;
        float s = 0.f;
        #pragma unroll
        for (int m = 0; m < M_UTT; ++m) s += base[m * D_DIM + d];
        c[r] = s * (1.0f / M_UTT);
        ss += c[r] * c[r];
    }
    __shared__ float red[256];
    red[t] = ss;
    __syncthreads();
    for (int ofs = 128; ofs > 0; ofs >>= 1) {
        if (t < ofs) red[t] += red[t + ofs];
        __syncthreads();
    }
    const float rn = 1.0f / fmaxf(sqrtf(red[0]), EPS);
    #pragma unroll
    for (int r = 0; r < 3; ++r) {
        const int d = t + r * 256;
        chat[(size_t)i * D_DIM + d] = __float2bfloat16(c[r] * rn);
    }
}

// ---------------------------------------------------------------------------
// Kernel 2: per-utterance L2 normalize; bf16 Ehat laid out [m][i][d] so GEMM
// row u = m*N + i (row tiles never cross an m boundary).
// ---------------------------------------------------------------------------
__global__ void ehat_kernel(const float* __restrict__ emb,
                            __hip_bfloat16* __restrict__ ehat) {
    const int u = blockIdx.x;
    const int i = u / M_UTT;
    const int m = u % M_UTT;
    const int t = threadIdx.x;
    const float* src = emb + ((size_t)i * M_UTT + m) * D_DIM;

    float v[3];
    float ss = 0.f;
    #pragma unroll
    for (int r = 0; r < 3; ++r) {
        v[r] = src[t + r * 256];
        ss += v[r] * v[r];
    }
    __shared__ float red[256];
    red[t] = ss;
    __syncthreads();
    for (int ofs = 128; ofs > 0; ofs >>= 1) {
        if (t < ofs) red[t] += red[t + ofs];
        __syncthreads();
    }
    const float rn = 1.0f / fmaxf(sqrtf(red[0]), EPS);
    __hip_bfloat16* dst = ehat + ((size_t)m * N_SPK + i) * D_DIM;
    #pragma unroll
    for (int r = 0; r < 3; ++r) dst[t + r * 256] = __float2bfloat16(v[r] * rn);
}

// ---------------------------------------------------------------------------
// Kernel 3: fused GEMM + partial online-softmax-over-i epilogue.
// 128x128 tile, BK=32, 4 waves (2x2), 4x4 MFMA 16x16x32 acc per wave.
// Block (bu,bj): rows u0=bu*128 (m = bu/8, rb = bu%8), cols j0=bj*128.
// Writes: Pmax/Psum[(m*8+rb)*1024 + j]  (per-column partial over 128 rows),
//         T[m*1024+j] = sim at target row i* = (m*1024+j)/20 (exactly one
//         block per (m,j) owns that row).
// A/B frag: row = lane&15, k = quad*8..  D frag: col = lane&15, row = quad*4+r
// (layouts verified in round 1).
// ---------------------------------------------------------------------------
__global__ void gemm_fused_kernel(const __hip_bfloat16* __restrict__ ehat,
                                  const __hip_bfloat16* __restrict__ chat,
                                  const float* __restrict__ wp,
                                  const float* __restrict__ bp,
                                  float* __restrict__ Pmax,
                                  float* __restrict__ Psum,
                                  float* __restrict__ T) {
    __shared__ __hip_bfloat16 As[128 * 32];
    __shared__ __hip_bfloat16 Bs[128 * 32];
    __shared__ float red[2][2][64][2];   // [wave_row][wave_col][col][{max,sum}]

    const int t = threadIdx.x;          // 0..255
    const int lane = t & 63;
    const int wid = t >> 6;             // 0..3
    const int wr = wid >> 1;            // wave row (0/1)
    const int wc = wid & 1;             // wave col (0/1)
    const int c = lane & 15;
    const int quad = lane >> 4;

    const int bu = blockIdx.x >> 3;     // 0..159
    const int bj = blockIdx.x & 7;      // 0..7
    const int m  = bu >> 3;             // 0..19
    const int rb = bu & 7;              // row-block within m
    const int u0 = bu * 128;            // global row in [M][N] flattened
    const int j0 = bj * 128;

    const short* Ag = (const short*)ehat + (size_t)u0 * D_DIM;
    const short* Bg = (const short*)chat + (size_t)j0 * D_DIM;

    // staging addresses: thread t covers row t/4 (+64*s), 8 shorts at col (t%4)*8
    const int srow = t >> 2;
    const int scol = (t & 3) * 8;

    floatx4 acc[4][4] = {};

    for (int k0 = 0; k0 < D_DIM; k0 += 32) {
        #pragma unroll
        for (int s = 0; s < 2; ++s) {
            const int row = srow + s * 64;
            load16_to_lds(Ag + (size_t)row * D_DIM + k0 + scol, As + row * 32 + scol);
            load16_to_lds(Bg + (size_t)row * D_DIM + k0 + scol, Bs + row * 32 + scol);
        }
        __syncthreads();

        short8 af[4], bf[4];
        #pragma unroll
        for (int it = 0; it < 4; ++it)
            af[it] = *(const short8*)((const short*)As + (wr * 64 + it * 16 + c) * 32 + quad * 8);
        #pragma unroll
        for (int jt = 0; jt < 4; ++jt)
            bf[jt] = *(const short8*)((const short*)Bs + (wc * 64 + jt * 16 + c) * 32 + quad * 8);

        #pragma unroll
        for (int it = 0; it < 4; ++it)
            #pragma unroll
            for (int jt = 0; jt < 4; ++jt)
                acc[it][jt] = __builtin_amdgcn_mfma_f32_16x16x32_bf16(af[it], bf[jt], acc[it][jt], 0, 0, 0);
        __syncthreads();
    }

    const float w = wp[0], b = bp[0];

    // ---- per-column (j) online-softmax partial over this block's 128 rows ----
    // lane holds rows: it*16 + quad*4 + r (within wave's 64), col jt*16 + c.
    float col_mx[4], col_sm[4];
    #pragma unroll
    for (int jt = 0; jt < 4; ++jt) {
        float mx = -1e30f;
        #pragma unroll
        for (int it = 0; it < 4; ++it)
            #pragma unroll
            for (int r = 0; r < 4; ++r)
                mx = fmaxf(mx, w * acc[it][jt][r] + b);
        float sm = 0.f;
        #pragma unroll
        for (int it = 0; it < 4; ++it)
            #pragma unroll
            for (int r = 0; r < 4; ++r)
                sm += __expf(w * acc[it][jt][r] + b - mx);
        // reduce across quads (lanes c, c+16, c+32, c+48 hold different rows)
        #pragma unroll
        for (int off = 16; off <= 32; off <<= 1) {
            const float omx = __shfl_xor(mx, off);
            const float osm = __shfl_xor(sm, off);
            const float nm = fmaxf(mx, omx);
            sm = sm * __expf(mx - nm) + osm * __expf(omx - nm);
            mx = nm;
        }
        col_mx[jt] = mx;
        col_sm[jt] = sm;
    }
    if (quad == 0) {
        #pragma unroll
        for (int jt = 0; jt < 4; ++jt) {
            red[wr][wc][jt * 16 + c][0] = col_mx[jt];
            red[wr][wc][jt * 16 + c][1] = col_sm[jt];
        }
    }

    // ---- target logit extraction: row within m-slab == (m*1024+col)/20 ----
    #pragma unroll
    for (int it = 0; it < 4; ++it) {
        #pragma unroll
        for (int jt = 0; jt < 4; ++jt) {
            const int col = j0 + wc * 64 + jt * 16 + c;
            const int g = m * N_SPK + col;
            const int istar = g / M_UTT;
            const int rbase = rb * 128 + wr * 64 + it * 16 + quad * 4;
            #pragma unroll
            for (int r = 0; r < 4; ++r) {
                if (rbase + r == istar) T[g] = acc[it][jt][r];
            }
        }
    }

    __syncthreads();
    if (wid < 2) {   // wr == 0, wc == wid
        const int cc = lane;              // 0..63
        const float m0 = red[0][wid][cc][0], s0 = red[0][wid][cc][1];
        const float m1 = red[1][wid][cc][0], s1 = red[1][wid][cc][1];
        const float nm = fmaxf(m0, m1);
        const float ns = s0 * __expf(m0 - nm) + s1 * __expf(m1 - nm);
        const int col = j0 + wid * 64 + cc;
        const int pidx = (m * 8 + rb) * N_SPK + col;
        Pmax[pidx] = nm;
        Psum[pidx] = ns;
    }
}

// ---------------------------------------------------------------------------
// Kernel 4: per-(m,j) combine of 8 row-block partials -> loss term; block sum.
// 80 blocks x 256 threads = 20480 items.
// ---------------------------------------------------------------------------
__global__ void combine_kernel(const float* __restrict__ Pmax,
                               const float* __restrict__ Psum,
                               const float* __restrict__ T,
                               const float* __restrict__ wp,
                               const float* __restrict__ bp,
                               float* __restrict__ part) {
    const int p = blockIdx.x * 256 + threadIdx.x;   // 0..20479
    const int m = p >> 10;
    const int j = p & 1023;
    const float w = wp[0], b = bp[0];

    float M0 = -1e30f, S = 0.f;
    #pragma unroll
    for (int rb = 0; rb < 8; ++rb) {
        const int q = (m * 8 + rb) * N_SPK + j;
        const float pm = Pmax[q], ps = Psum[q];
        const float nm = fmaxf(M0, pm);
        S = S * __expf(M0 - nm) + ps * __expf(pm - nm);
        M0 = nm;
    }
    const float lse = M0 + __logf(S);
    const float term = (w * T[p] + b) - lse;

    __shared__ float red[256];
    red[threadIdx.x] = term;
    __syncthreads();
    for (int o = 128; o > 0; o >>= 1) {
        if (threadIdx.x < o) red[threadIdx.x] += red[threadIdx.x + o];
        __syncthreads();
    }
    if (threadIdx.x == 0) part[blockIdx.x] = red[0];
}

__global__ void final_kernel(const float* __restrict__ part,
                             float* __restrict__ out) {
    __shared__ float red[128];
    const int t = threadIdx.x;
    red[t] = (t < 80) ? part[t] : 0.f;
    __syncthreads();
    for (int o = 64; o > 0; o >>= 1) {
        if (t < o) red[t] += red[t + o];
        __syncthreads();
    }
    if (t == 0) out[0] = -red[0] / (float)NM_ROWS;
}

// ---------------------------------------------------------------------------
extern "C" void kernel_launch(void* const* d_in, const int* in_sizes, int n_in,
                              void* d_out, int out_size, void* d_ws, size_t ws_size,
                              hipStream_t stream) {
    const float* emb = (const float*)d_in[0];
    const float* wp  = (const float*)d_in[1];
    const float* bp  = (const float*)d_in[2];
    float* out = (float*)d_out;

    char* ws = (char*)d_ws;
    // layout (bytes, all 256-aligned):
    //   Ehat bf16 [M][N][D] : 31,457,280                       @ 0
    //   Chat bf16 [N][D]    :  1,572,864                       @ 31,457,280
    //   Pmax f32 [20*8][N]  :    655,360                       @ 33,030,144
    //   Psum f32 [20*8][N]  :    655,360                       @ 33,685,504
    //   T    f32 [M][N]     :     81,920                       @ 34,340,864
    //   part f32 [80]       :        320                       @ 34,422,784
    __hip_bfloat16* ehat = (__hip_bfloat16*)(ws);
    __hip_bfloat16* chat = (__hip_bfloat16*)(ws + 31457280);
    float* Pmax = (float*)(ws + 33030144);
    float* Psum = (float*)(ws + 33685504);
    float* T    = (float*)(ws + 34340864);
    float* part = (float*)(ws + 34422784);

    centroid_kernel<<<dim3(N_SPK), dim3(256), 0, stream>>>(emb, chat);
    ehat_kernel<<<dim3(NM_ROWS), dim3(256), 0, stream>>>(emb, ehat);
    gemm_fused_kernel<<<dim3(160 * 8), dim3(256), 0, stream>>>(ehat, chat, wp, bp, Pmax, Psum, T);
    combine_kernel<<<dim3(80), dim3(256), 0, stream>>>(Pmax, Psum, T, wp, bp, part);
    final_kernel<<<dim3(1), dim3(128), 0, stream>>>(part, out);
}

// Round 3
// 167.405 us; speedup vs baseline: 3.5505x; 1.2530x over previous
//
#include <hip/hip_runtime.h>
#include <hip/hip_bf16.h>
#include <cstdint>

#define N_SPK 1024
#define M_UTT 20
#define D_DIM 768
#define NM_ROWS (N_SPK * M_UTT)   // 20480 utterances / rows

static constexpr float EPS = 1e-8f;

typedef __attribute__((ext_vector_type(8))) short short8;   // 8 x bf16 (4 VGPRs)
typedef __attribute__((ext_vector_type(4))) float floatx4;  // MFMA accumulator

__device__ __forceinline__ void load16_to_lds(const void* g, void* l) {
    __builtin_amdgcn_global_load_lds(
        (const __attribute__((address_space(1))) uint32_t*)g,
        (__attribute__((address_space(3))) uint32_t*)l, 16, 0, 0);
}

__device__ __forceinline__ unsigned short bf16bits(float x) {
    __hip_bfloat16 h = __float2bfloat16(x);
    return *(unsigned short*)&h;
}

__device__ __forceinline__ float wave_sum(float v) {
    #pragma unroll
    for (int o = 32; o > 0; o >>= 1) v += __shfl_xor(v, o);
    return v;
}

// ---------------------------------------------------------------------------
// Kernel 1 (fused prep): per speaker, read emb once (float4), compute
// centroid + centroid norm + 20 utterance norms, write bf16 Chat and Ehat
// ([m][i][d] layout) with ushort4 packed stores.
// Block = 192 threads (3 waves); thread t owns float4 column t (768/4=192).
// ---------------------------------------------------------------------------
__global__ __launch_bounds__(192) void prep_kernel(const float* __restrict__ emb,
                                                   __hip_bfloat16* __restrict__ ehat,
                                                   __hip_bfloat16* __restrict__ chat) {
    const int i = blockIdx.x;      // speaker
    const int t = threadIdx.x;     // 0..191
    const int wave = t >> 6, lane = t & 63;
    const float4* src = (const float4*)(emb + (size_t)i * M_UTT * D_DIM);

    float4 v[M_UTT];
    float ss[M_UTT];
    float4 cen = {0.f, 0.f, 0.f, 0.f};
    #pragma unroll
    for (int m = 0; m < M_UTT; ++m) {
        const float4 x = src[m * 192 + t];
        v[m] = x;
        ss[m] = x.x * x.x + x.y * x.y + x.z * x.z + x.w * x.w;
        cen.x += x.x; cen.y += x.y; cen.z += x.z; cen.w += x.w;
    }
    cen.x *= (1.f / M_UTT); cen.y *= (1.f / M_UTT);
    cen.z *= (1.f / M_UTT); cen.w *= (1.f / M_UTT);
    float css = cen.x * cen.x + cen.y * cen.y + cen.z * cen.z + cen.w * cen.w;

    __shared__ float red[M_UTT + 1][3];
    #pragma unroll
    for (int m = 0; m < M_UTT; ++m) {
        const float s = wave_sum(ss[m]);
        if (lane == 0) red[m][wave] = s;
    }
    {
        const float s = wave_sum(css);
        if (lane == 0) red[M_UTT][wave] = s;
    }
    __syncthreads();

    #pragma unroll
    for (int m = 0; m < M_UTT; ++m) {
        const float tot = red[m][0] + red[m][1] + red[m][2];
        const float rn = 1.0f / fmaxf(sqrtf(tot), EPS);
        ushort4 o;
        o.x = bf16bits(v[m].x * rn); o.y = bf16bits(v[m].y * rn);
        o.z = bf16bits(v[m].z * rn); o.w = bf16bits(v[m].w * rn);
        *(ushort4*)((unsigned short*)ehat + ((size_t)(m * N_SPK + i)) * D_DIM + 4 * t) = o;
    }
    {
        const float tot = red[M_UTT][0] + red[M_UTT][1] + red[M_UTT][2];
        const float rn = 1.0f / fmaxf(sqrtf(tot), EPS);
        ushort4 o;
        o.x = bf16bits(cen.x * rn); o.y = bf16bits(cen.y * rn);
        o.z = bf16bits(cen.z * rn); o.w = bf16bits(cen.w * rn);
        *(ushort4*)((unsigned short*)chat + (size_t)i * D_DIM + 4 * t) = o;
    }
}

// ---------------------------------------------------------------------------
// Kernel 2: fused GEMM + partial online-softmax epilogue.
// 128x128 tile, BK=32, 4 waves (2x2), 4x4 MFMA 16x16x32 per wave.
// XCD-aware swizzle: blk&7 = XCD owns bu-slab [xcd*20, xcd*20+20) x all bj
// (per-XCD L2: 3.9 MB A slab streamed + 1.5 MB B resident).
// LDS: 16B chunks at [row][qs] where global k-octet q = qs ^ ((row>>1)&3) --
// XOR swizzle keeps staging (base+lane*16, 64B-contig global) AND makes
// ds_read_b128 phases hit every bank <=2x (free).
// ---------------------------------------------------------------------------
__global__ void gemm_fused_kernel(const __hip_bfloat16* __restrict__ ehat,
                                  const __hip_bfloat16* __restrict__ chat,
                                  const float* __restrict__ wp,
                                  const float* __restrict__ bp,
                                  float* __restrict__ Pmax,
                                  float* __restrict__ Psum,
                                  float* __restrict__ T) {
    __shared__ __hip_bfloat16 As[128 * 32];
    __shared__ __hip_bfloat16 Bs[128 * 32];
    __shared__ float red[2][2][64][2];

    const int t = threadIdx.x;
    const int lane = t & 63;
    const int wid = t >> 6;
    const int wr = wid >> 1;
    const int wc = wid & 1;
    const int c = lane & 15;
    const int quad = lane >> 4;

    // XCD-aware decode
    const int xcd = blockIdx.x & 7;
    const int idx = blockIdx.x >> 3;        // 0..159
    const int bu  = xcd * 20 + (idx >> 3);  // 0..159
    const int bj  = idx & 7;
    const int m   = bu >> 3;
    const int rb  = bu & 7;
    const int u0  = bu * 128;
    const int j0  = bj * 128;

    const short* Ag = (const short*)ehat + (size_t)u0 * D_DIM;
    const short* Bg = (const short*)chat + (size_t)j0 * D_DIM;

    floatx4 acc[4][4] = {};

    for (int k0 = 0; k0 < D_DIM; k0 += 32) {
        #pragma unroll
        for (int s = 0; s < 2; ++s) {
            const int ci  = s * 256 + t;               // chunk index 0..511
            const int row = ci >> 2;
            const int q   = (ci & 3) ^ ((row >> 1) & 3);
            load16_to_lds(Ag + (size_t)row * D_DIM + k0 + q * 8, (short*)As + ci * 8);
            load16_to_lds(Bg + (size_t)row * D_DIM + k0 + q * 8, (short*)Bs + ci * 8);
        }
        __syncthreads();

        short8 af[4], bf[4];
        #pragma unroll
        for (int it = 0; it < 4; ++it) {
            const int r = wr * 64 + it * 16 + c;
            const int slot = r * 4 + (quad ^ ((r >> 1) & 3));
            af[it] = *(const short8*)((const short*)As + slot * 8);
        }
        #pragma unroll
        for (int jt = 0; jt < 4; ++jt) {
            const int r = wc * 64 + jt * 16 + c;
            const int slot = r * 4 + (quad ^ ((r >> 1) & 3));
            bf[jt] = *(const short8*)((const short*)Bs + slot * 8);
        }

        #pragma unroll
        for (int it = 0; it < 4; ++it)
            #pragma unroll
            for (int jt = 0; jt < 4; ++jt)
                acc[it][jt] = __builtin_amdgcn_mfma_f32_16x16x32_bf16(af[it], bf[jt], acc[it][jt], 0, 0, 0);
        __syncthreads();
    }

    const float w = wp[0], b = bp[0];

    // per-column online-softmax partial over this block's 128 rows
    float col_mx[4], col_sm[4];
    #pragma unroll
    for (int jt = 0; jt < 4; ++jt) {
        float mx = -1e30f;
        #pragma unroll
        for (int it = 0; it < 4; ++it)
            #pragma unroll
            for (int r = 0; r < 4; ++r)
                mx = fmaxf(mx, w * acc[it][jt][r] + b);
        float sm = 0.f;
        #pragma unroll
        for (int it = 0; it < 4; ++it)
            #pragma unroll
            for (int r = 0; r < 4; ++r)
                sm += __expf(w * acc[it][jt][r] + b - mx);
        #pragma unroll
        for (int off = 16; off <= 32; off <<= 1) {
            const float omx = __shfl_xor(mx, off);
            const float osm = __shfl_xor(sm, off);
            const float nm = fmaxf(mx, omx);
            sm = sm * __expf(mx - nm) + osm * __expf(omx - nm);
            mx = nm;
        }
        col_mx[jt] = mx;
        col_sm[jt] = sm;
    }
    if (quad == 0) {
        #pragma unroll
        for (int jt = 0; jt < 4; ++jt) {
            red[wr][wc][jt * 16 + c][0] = col_mx[jt];
            red[wr][wc][jt * 16 + c][1] = col_sm[jt];
        }
    }

    // target logit: i (within m-slab) == (m*1024+col)/20
    #pragma unroll
    for (int it = 0; it < 4; ++it) {
        #pragma unroll
        for (int jt = 0; jt < 4; ++jt) {
            const int col = j0 + wc * 64 + jt * 16 + c;
            const int g = m * N_SPK + col;
            const int istar = g / M_UTT;
            const int rbase = rb * 128 + wr * 64 + it * 16 + quad * 4;
            #pragma unroll
            for (int r = 0; r < 4; ++r) {
                if (rbase + r == istar) T[g] = acc[it][jt][r];
            }
        }
    }

    __syncthreads();
    if (wid < 2) {
        const int cc = lane;
        const float m0 = red[0][wid][cc][0], s0 = red[0][wid][cc][1];
        const float m1 = red[1][wid][cc][0], s1 = red[1][wid][cc][1];
        const float nm = fmaxf(m0, m1);
        const float ns = s0 * __expf(m0 - nm) + s1 * __expf(m1 - nm);
        const int col = j0 + wid * 64 + cc;
        const int pidx = (m * 8 + rb) * N_SPK + col;
        Pmax[pidx] = nm;
        Psum[pidx] = ns;
    }
}

// ---------------------------------------------------------------------------
// Kernel 3: combine 8 row-block partials per (m,j) -> loss term; block sum.
// ---------------------------------------------------------------------------
__global__ void combine_kernel(const float* __restrict__ Pmax,
                               const float* __restrict__ Psum,
                               const float* __restrict__ T,
                               const float* __restrict__ wp,
                               const float* __restrict__ bp,
                               float* __restrict__ part) {
    const int p = blockIdx.x * 256 + threadIdx.x;
    const int m = p >> 10;
    const int j = p & 1023;
    const float w = wp[0], b = bp[0];

    float M0 = -1e30f, S = 0.f;
    #pragma unroll
    for (int rb = 0; rb < 8; ++rb) {
        const int q = (m * 8 + rb) * N_SPK + j;
        const float pm = Pmax[q], ps = Psum[q];
        const float nm = fmaxf(M0, pm);
        S = S * __expf(M0 - nm) + ps * __expf(pm - nm);
        M0 = nm;
    }
    const float lse = M0 + __logf(S);
    const float term = (w * T[p] + b) - lse;

    __shared__ float red[256];
    red[threadIdx.x] = term;
    __syncthreads();
    for (int o = 128; o > 0; o >>= 1) {
        if (threadIdx.x < o) red[threadIdx.x] += red[threadIdx.x + o];
        __syncthreads();
    }
    if (threadIdx.x == 0) part[blockIdx.x] = red[0];
}

__global__ void final_kernel(const float* __restrict__ part,
                             float* __restrict__ out) {
    __shared__ float red[128];
    const int t = threadIdx.x;
    red[t] = (t < 80) ? part[t] : 0.f;
    __syncthreads();
    for (int o = 64; o > 0; o >>= 1) {
        if (t < o) red[t] += red[t + o];
        __syncthreads();
    }
    if (t == 0) out[0] = -red[0] / (float)NM_ROWS;
}

// ---------------------------------------------------------------------------
extern "C" void kernel_launch(void* const* d_in, const int* in_sizes, int n_in,
                              void* d_out, int out_size, void* d_ws, size_t ws_size,
                              hipStream_t stream) {
    const float* emb = (const float*)d_in[0];
    const float* wp  = (const float*)d_in[1];
    const float* bp  = (const float*)d_in[2];
    float* out = (float*)d_out;

    char* ws = (char*)d_ws;
    //   Ehat bf16 [M][N][D] : 31,457,280  @ 0
    //   Chat bf16 [N][D]    :  1,572,864  @ 31,457,280
    //   Pmax f32 [160][N]   :    655,360  @ 33,030,144
    //   Psum f32 [160][N]   :    655,360  @ 33,685,504
    //   T    f32 [M][N]     :     81,920  @ 34,340,864
    //   part f32 [80]       :        320  @ 34,422,784
    __hip_bfloat16* ehat = (__hip_bfloat16*)(ws);
    __hip_bfloat16* chat = (__hip_bfloat16*)(ws + 31457280);
    float* Pmax = (float*)(ws + 33030144);
    float* Psum = (float*)(ws + 33685504);
    float* T    = (float*)(ws + 34340864);
    float* part = (float*)(ws + 34422784);

    prep_kernel<<<dim3(N_SPK), dim3(192), 0, stream>>>(emb, ehat, chat);
    gemm_fused_kernel<<<dim3(160 * 8), dim3(256), 0, stream>>>(ehat, chat, wp, bp, Pmax, Psum, T);
    combine_kernel<<<dim3(80), dim3(256), 0, stream>>>(Pmax, Psum, T, wp, bp, part);
    final_kernel<<<dim3(1), dim3(128), 0, stream>>>(part, out);
}

// Round 4
// 162.570 us; speedup vs baseline: 3.6561x; 1.0297x over previous
//
#include <hip/hip_runtime.h>
#include <hip/hip_bf16.h>
#include <cstdint>

#define N_SPK 1024
#define M_UTT 20
#define D_DIM 768
#define NM_ROWS (N_SPK * M_UTT)   // 20480 utterances / rows

static constexpr float EPS = 1e-8f;

typedef __attribute__((ext_vector_type(8))) short short8;   // 8 x bf16 (4 VGPRs)
typedef __attribute__((ext_vector_type(4))) float floatx4;  // MFMA accumulator

__device__ __forceinline__ void load16_to_lds(const void* g, void* l) {
    __builtin_amdgcn_global_load_lds(
        (const __attribute__((address_space(1))) uint32_t*)g,
        (__attribute__((address_space(3))) uint32_t*)l, 16, 0, 0);
}

__device__ __forceinline__ unsigned short bf16bits(float x) {
    __hip_bfloat16 h = __float2bfloat16(x);
    return *(unsigned short*)&h;
}

__device__ __forceinline__ float wave_sum(float v) {
    #pragma unroll
    for (int o = 32; o > 0; o >>= 1) v += __shfl_xor(v, o);
    return v;
}

// ---------------------------------------------------------------------------
// Kernel 1 (fused prep): per speaker, read emb once (float2/thread, 384 thr =
// 6 waves for low VGPR pressure + high occupancy), compute centroid norm +
// 20 utterance norms, write bf16 Chat and Ehat ([m][i][d]) with ushort2.
// ---------------------------------------------------------------------------
__global__ __launch_bounds__(384) void prep_kernel(const float* __restrict__ emb,
                                                   __hip_bfloat16* __restrict__ ehat,
                                                   __hip_bfloat16* __restrict__ chat) {
    const int i = blockIdx.x;      // speaker
    const int t = threadIdx.x;     // 0..383
    const int wave = t >> 6, lane = t & 63;
    const float2* src = (const float2*)(emb + (size_t)i * M_UTT * D_DIM);

    float2 v[M_UTT];
    float ss[M_UTT];
    float2 cen = {0.f, 0.f};
    #pragma unroll
    for (int m = 0; m < M_UTT; ++m) {
        const float2 x = src[m * 384 + t];
        v[m] = x;
        ss[m] = x.x * x.x + x.y * x.y;
        cen.x += x.x; cen.y += x.y;
    }
    cen.x *= (1.f / M_UTT); cen.y *= (1.f / M_UTT);
    float css = cen.x * cen.x + cen.y * cen.y;

    __shared__ float red[M_UTT + 1][6];
    #pragma unroll
    for (int m = 0; m < M_UTT; ++m) {
        const float s = wave_sum(ss[m]);
        if (lane == 0) red[m][wave] = s;
    }
    {
        const float s = wave_sum(css);
        if (lane == 0) red[M_UTT][wave] = s;
    }
    __syncthreads();

    #pragma unroll
    for (int m = 0; m < M_UTT; ++m) {
        const float tot = red[m][0] + red[m][1] + red[m][2] +
                          red[m][3] + red[m][4] + red[m][5];
        const float rn = 1.0f / fmaxf(sqrtf(tot), EPS);
        ushort2 o;
        o.x = bf16bits(v[m].x * rn); o.y = bf16bits(v[m].y * rn);
        *(ushort2*)((unsigned short*)ehat + ((size_t)(m * N_SPK + i)) * D_DIM + 2 * t) = o;
    }
    {
        const float tot = red[M_UTT][0] + red[M_UTT][1] + red[M_UTT][2] +
                          red[M_UTT][3] + red[M_UTT][4] + red[M_UTT][5];
        const float rn = 1.0f / fmaxf(sqrtf(tot), EPS);
        ushort2 o;
        o.x = bf16bits(cen.x * rn); o.y = bf16bits(cen.y * rn);
        *(ushort2*)((unsigned short*)chat + (size_t)i * D_DIM + 2 * t) = o;
    }
}

// ---------------------------------------------------------------------------
// Kernel 2: fused GEMM + partial online-softmax epilogue.
// 128x64 tile, BK=32, TWO waves (rows 0-63 / 64-127), 4x4 MFMA 16x16x32 per
// wave. 2560 blocks = 10/CU, ~13 KB LDS -> 8 blocks/CU co-resident (16 waves)
// vs R3's 4x4-wave 5-blocks-in-4-slots structure (32% occupancy, lone-block
// tail round). Per-wave instruction stream unchanged from R3.
// XCD swizzle: blk&7 = XCD owns bu-slab [xcd*20,xcd*20+20) x all 16 bj.
// LDS XOR swizzle: 16B chunk q = qs ^ ((row>>1)&3) (bank-conflict-free,
// verified 0 conflicts in R3).
// ---------------------------------------------------------------------------
__global__ __launch_bounds__(128) void gemm_fused_kernel(
        const __hip_bfloat16* __restrict__ ehat,
        const __hip_bfloat16* __restrict__ chat,
        const float* __restrict__ wp,
        const float* __restrict__ bp,
        float* __restrict__ Pmax,
        float* __restrict__ Psum,
        float* __restrict__ T) {
    __shared__ __hip_bfloat16 As[128 * 32];
    __shared__ __hip_bfloat16 Bs[64 * 32];
    __shared__ float red[2][64][2];

    const int t = threadIdx.x;          // 0..127
    const int lane = t & 63;
    const int wid = t >> 6;             // wave: row half 0/1
    const int c = lane & 15;
    const int quad = lane >> 4;

    const int xcd = blockIdx.x & 7;
    const int idx = blockIdx.x >> 3;        // 0..319
    const int bu  = xcd * 20 + (idx >> 4);  // 0..159
    const int bj  = idx & 15;               // 0..15
    const int m   = bu >> 3;
    const int rb  = bu & 7;
    const int u0  = bu * 128;
    const int j0  = bj * 64;

    const short* Ag = (const short*)ehat + (size_t)u0 * D_DIM;
    const short* Bg = (const short*)chat + (size_t)j0 * D_DIM;

    floatx4 acc[4][4] = {};

    for (int k0 = 0; k0 < D_DIM; k0 += 32) {
        #pragma unroll
        for (int s = 0; s < 4; ++s) {          // A: 512 16B chunks
            const int ci  = s * 128 + t;
            const int row = ci >> 2;
            const int q   = (ci & 3) ^ ((row >> 1) & 3);
            load16_to_lds(Ag + (size_t)row * D_DIM + k0 + q * 8, (short*)As + ci * 8);
        }
        #pragma unroll
        for (int s = 0; s < 2; ++s) {          // B: 256 16B chunks
            const int ci  = s * 128 + t;
            const int row = ci >> 2;
            const int q   = (ci & 3) ^ ((row >> 1) & 3);
            load16_to_lds(Bg + (size_t)row * D_DIM + k0 + q * 8, (short*)Bs + ci * 8);
        }
        __syncthreads();

        short8 af[4], bf[4];
        #pragma unroll
        for (int it = 0; it < 4; ++it) {
            const int r = wid * 64 + it * 16 + c;
            const int slot = r * 4 + (quad ^ ((r >> 1) & 3));
            af[it] = *(const short8*)((const short*)As + slot * 8);
        }
        #pragma unroll
        for (int jt = 0; jt < 4; ++jt) {
            const int r = jt * 16 + c;
            const int slot = r * 4 + (quad ^ ((r >> 1) & 3));
            bf[jt] = *(const short8*)((const short*)Bs + slot * 8);
        }

        #pragma unroll
        for (int it = 0; it < 4; ++it)
            #pragma unroll
            for (int jt = 0; jt < 4; ++jt)
                acc[it][jt] = __builtin_amdgcn_mfma_f32_16x16x32_bf16(af[it], bf[jt], acc[it][jt], 0, 0, 0);
        __syncthreads();
    }

    const float w = wp[0], b = bp[0];

    // per-column online-softmax partial over the wave's 64 rows
    float col_mx[4], col_sm[4];
    #pragma unroll
    for (int jt = 0; jt < 4; ++jt) {
        float mx = -1e30f;
        #pragma unroll
        for (int it = 0; it < 4; ++it)
            #pragma unroll
            for (int r = 0; r < 4; ++r)
                mx = fmaxf(mx, w * acc[it][jt][r] + b);
        float sm = 0.f;
        #pragma unroll
        for (int it = 0; it < 4; ++it)
            #pragma unroll
            for (int r = 0; r < 4; ++r)
                sm += __expf(w * acc[it][jt][r] + b - mx);
        #pragma unroll
        for (int off = 16; off <= 32; off <<= 1) {
            const float omx = __shfl_xor(mx, off);
            const float osm = __shfl_xor(sm, off);
            const float nm = fmaxf(mx, omx);
            sm = sm * __expf(mx - nm) + osm * __expf(omx - nm);
            mx = nm;
        }
        col_mx[jt] = mx;
        col_sm[jt] = sm;
    }
    if (quad == 0) {
        #pragma unroll
        for (int jt = 0; jt < 4; ++jt) {
            red[wid][jt * 16 + c][0] = col_mx[jt];
            red[wid][jt * 16 + c][1] = col_sm[jt];
        }
    }

    // target logit: row within m-slab == (m*1024+col)/20
    #pragma unroll
    for (int it = 0; it < 4; ++it) {
        #pragma unroll
        for (int jt = 0; jt < 4; ++jt) {
            const int col = j0 + jt * 16 + c;
            const int g = m * N_SPK + col;
            const int istar = g / M_UTT;
            const int rbase = rb * 128 + wid * 64 + it * 16 + quad * 4;
            #pragma unroll
            for (int r = 0; r < 4; ++r) {
                if (rbase + r == istar) T[g] = acc[it][jt][r];
            }
        }
    }

    __syncthreads();
    if (wid == 0) {   // wave 0 merges the two row-halves
        const int cc = lane;              // 0..63
        const float m0 = red[0][cc][0], s0 = red[0][cc][1];
        const float m1 = red[1][cc][0], s1 = red[1][cc][1];
        const float nm = fmaxf(m0, m1);
        const float ns = s0 * __expf(m0 - nm) + s1 * __expf(m1 - nm);
        const int col = j0 + cc;
        const int pidx = (m * 8 + rb) * N_SPK + col;
        Pmax[pidx] = nm;
        Psum[pidx] = ns;
    }
}

// ---------------------------------------------------------------------------
// Kernel 3: combine 8 row-block partials per (m,j) -> loss term; block sum.
// ---------------------------------------------------------------------------
__global__ void combine_kernel(const float* __restrict__ Pmax,
                               const float* __restrict__ Psum,
                               const float* __restrict__ T,
                               const float* __restrict__ wp,
                               const float* __restrict__ bp,
                               float* __restrict__ part) {
    const int p = blockIdx.x * 256 + threadIdx.x;
    const int m = p >> 10;
    const int j = p & 1023;
    const float w = wp[0], b = bp[0];

    float M0 = -1e30f, S = 0.f;
    #pragma unroll
    for (int rb = 0; rb < 8; ++rb) {
        const int q = (m * 8 + rb) * N_SPK + j;
        const float pm = Pmax[q], ps = Psum[q];
        const float nm = fmaxf(M0, pm);
        S = S * __expf(M0 - nm) + ps * __expf(pm - nm);
        M0 = nm;
    }
    const float lse = M0 + __logf(S);
    const float term = (w * T[p] + b) - lse;

    __shared__ float red[256];
    red[threadIdx.x] = term;
    __syncthreads();
    for (int o = 128; o > 0; o >>= 1) {
        if (threadIdx.x < o) red[threadIdx.x] += red[threadIdx.x + o];
        __syncthreads();
    }
    if (threadIdx.x == 0) part[blockIdx.x] = red[0];
}

__global__ void final_kernel(const float* __restrict__ part,
                             float* __restrict__ out) {
    __shared__ float red[128];
    const int t = threadIdx.x;
    red[t] = (t < 80) ? part[t] : 0.f;
    __syncthreads();
    for (int o = 64; o > 0; o >>= 1) {
        if (t < o) red[t] += red[t + o];
        __syncthreads();
    }
    if (t == 0) out[0] = -red[0] / (float)NM_ROWS;
}

// ---------------------------------------------------------------------------
extern "C" void kernel_launch(void* const* d_in, const int* in_sizes, int n_in,
                              void* d_out, int out_size, void* d_ws, size_t ws_size,
                              hipStream_t stream) {
    const float* emb = (const float*)d_in[0];
    const float* wp  = (const float*)d_in[1];
    const float* bp  = (const float*)d_in[2];
    float* out = (float*)d_out;

    char* ws = (char*)d_ws;
    //   Ehat bf16 [M][N][D] : 31,457,280  @ 0
    //   Chat bf16 [N][D]    :  1,572,864  @ 31,457,280
    //   Pmax f32 [160][N]   :    655,360  @ 33,030,144
    //   Psum f32 [160][N]   :    655,360  @ 33,685,504
    //   T    f32 [M][N]     :     81,920  @ 34,340,864
    //   part f32 [80]       :        320  @ 34,422,784
    __hip_bfloat16* ehat = (__hip_bfloat16*)(ws);
    __hip_bfloat16* chat = (__hip_bfloat16*)(ws + 31457280);
    float* Pmax = (float*)(ws + 33030144);
    float* Psum = (float*)(ws + 33685504);
    float* T    = (float*)(ws + 34340864);
    float* part = (float*)(ws + 34422784);

    prep_kernel<<<dim3(N_SPK), dim3(384), 0, stream>>>(emb, ehat, chat);
    gemm_fused_kernel<<<dim3(160 * 16), dim3(128), 0, stream>>>(ehat, chat, wp, bp, Pmax, Psum, T);
    combine_kernel<<<dim3(80), dim3(256), 0, stream>>>(Pmax, Psum, T, wp, bp, part);
    final_kernel<<<dim3(1), dim3(128), 0, stream>>>(part, out);
}